// Round 1
// 1048.997 us; speedup vs baseline: 1.0222x; 1.0222x over previous
//
#include <hip/hip_runtime.h>
#include <hip/hip_bf16.h>

// B=2, S=2048, W=32, D=1024, H=16, hd=64
// Pipeline (full path, needs 800 MiB ws):
//   bf16-cast: Wq,Wk,Wv,Wo,q (small), k,v (big)
//   K/V GEMM: gemm_big = 256x256 tile, BK=64, 8-phase HK-style schedule
//             (T3+T4 counted vmcnt(4), T2 chunk-XOR swizzle, T5 setprio,
//             T1 XCD-grouped mapping). 8 waves = 2(M)x4(N), wave 128x64,
//             acc[8][4]. LDS = 2 dbuf x (A 256x64 + B 256x64) = 128 KiB.
//   Q/O GEMM: gemm_lds (128x128, verified rounds 2-3)
//   attn: per (b,s') head-softmax gather-attention -> A (4096x1024 bf16)
//   out  = A@Wo^T+bo (fp32)

#define DEVI __device__ __forceinline__

typedef __attribute__((ext_vector_type(8))) short bf16x8;
typedef __attribute__((ext_vector_type(4))) float f32x4;
typedef const __attribute__((address_space(1))) void* gvp;
typedef __attribute__((address_space(3))) void* lvp;

DEVI ushort f2bf(float f) {
  uint u = __float_as_uint(f);
  u = u + 0x7fffu + ((u >> 16) & 1u);
  return (ushort)(u >> 16);
}
DEVI float bf2f(ushort u) { return __uint_as_float(((uint)u) << 16); }

// ---------------- elementwise fp32 -> bf16 cast (RNE), 8 elems/thread ----
__global__ __launch_bounds__(256) void cast_kernel(const float* __restrict__ in,
                                                   ushort* __restrict__ out,
                                                   long n) {
  long i = ((long)blockIdx.x * 256 + threadIdx.x) * 8;
  const long stride = (long)gridDim.x * 256 * 8;
  for (; i < n; i += stride) {
    float4 a = *reinterpret_cast<const float4*>(in + i);
    float4 b = *reinterpret_cast<const float4*>(in + i + 4);
    ushort o[8];
    o[0] = f2bf(a.x); o[1] = f2bf(a.y); o[2] = f2bf(a.z); o[3] = f2bf(a.w);
    o[4] = f2bf(b.x); o[5] = f2bf(b.y); o[6] = f2bf(b.z); o[7] = f2bf(b.w);
    *reinterpret_cast<int4*>(out + i) = *reinterpret_cast<const int4*>(o);
  }
}

// ---------------- 8-phase bf16 GEMM: C = A @ W^T + bias (bf16 out) --------
// Tile 256(M)x256(N), K=1024, BK=64, NT=16 K-tiles, 8 outer iters x 2 tiles.
// 512 thr = 8 waves (2 M x 4 N), wave-tile 128x64, acc[8][4] of 16x16x32.
// LDS per dbuf slot: A0(rows0-127)@0, A1@16K, B0@32K, B1@48K (16 KiB each,
// row=128B=8 chunks of 16B, stored chunk p holds source chunk p^(row&7)).
// buf0 @0 holds even K-tiles, buf1 @64K odd ones.
// Staging: one half-tile (2 global_load_lds/thread) per phase:
//   ph1: B0(j+1)->buf1   ph2: B1(j+1)->buf1   ph3: A0(j+2)->buf0
//   ph4: A1(j+2)->buf0   ph5: B0(j+2)->buf0   ph6: B1(j+2)->buf0
//   ph7: A0(j+3)->buf1   ph8: A1(j+3)->buf1
// Region-overwrite safety: buf0.A reads complete by ph2-end barrier (stage
// ph3+), buf0.B reads by ph3-end (stage ph5+); mirrored for buf1.
// Drains: vmcnt(4) at ph4/ph8 ends (2 half-tiles stay in flight); last iter
// ph4 drains to 0.
template <int FI0, int FJ0>
DEVI void mfma16(f32x4 (&acc)[8][4], const bf16x8 (&A)[4][2],
                 const bf16x8 (&B)[2][2]) {
  __builtin_amdgcn_s_setprio(1);
#pragma unroll
  for (int i = 0; i < 4; ++i)
#pragma unroll
    for (int j = 0; j < 2; ++j)
#pragma unroll
      for (int kk = 0; kk < 2; ++kk)
        acc[FI0 + i][FJ0 + j] = __builtin_amdgcn_mfma_f32_16x16x32_bf16(
            A[i][kk], B[j][kk], acc[FI0 + i][FJ0 + j], 0, 0, 0);
  __builtin_amdgcn_s_setprio(0);
}

__global__ __launch_bounds__(512, 2) void gemm_big(const ushort* __restrict__ Ag,
                                                   const ushort* __restrict__ Wg,
                                                   const float* __restrict__ bias,
                                                   ushort* __restrict__ Cg) {
  constexpr int K = 1024;
  __shared__ char lds[131072];
  const int tid = threadIdx.x;
  const int lane = tid & 63;
  const int wave = tid >> 6;
  const int wm = wave >> 2;  // 0..1 (M half, 128 rows)
  const int wn = wave & 3;   // 0..3 (N quarter, 64 cols)
  const int d = blockIdx.x;
  const int bn = (d >> 3) & 3;
  const size_t bm = (size_t)(d & 7) * (gridDim.x >> 5) + (d >> 5);

  const ushort* aB = Ag + bm * 256 * K;
  const ushort* bB = Wg + (size_t)bn * 256 * K;

  // ---- staging addresses: thread t covers chunks t and t+512 of a half ----
  // chunk f: row=f>>3, pos=f&7, source chunk c=(f&7)^(row&7); note row+64
  // keeps the same c. Dest byte = f*16 (linear, wave-uniform+lane*16).
  const int r0 = tid >> 3;
  const int c0 = (tid & 7) ^ (r0 & 7);
  const ushort* aS0 = aB + (size_t)r0 * K + c0 * 8;
  const ushort* aS1 = aB + (size_t)(r0 + 64) * K + c0 * 8;
  const ushort* aS2 = aB + (size_t)(r0 + 128) * K + c0 * 8;
  const ushort* aS3 = aB + (size_t)(r0 + 192) * K + c0 * 8;
  const ushort* bS0 = bB + (size_t)r0 * K + c0 * 8;
  const ushort* bS1 = bB + (size_t)(r0 + 64) * K + c0 * 8;
  const ushort* bS2 = bB + (size_t)(r0 + 128) * K + c0 * 8;
  const ushort* bS3 = bB + (size_t)(r0 + 192) * K + c0 * 8;
  const int dst0 = tid * 16;
  const int dst1 = tid * 16 + 8192;

  // ---- fragment-read offsets: lane=16q+lm reads row lm, k-chunk kk*4+q ----
  const int lm = lane & 15;
  const int q = lane >> 4;
  const int rowB = lm * 128;
  const int swz0 = (q ^ (lm & 7)) * 16;        // kk=0
  const int swz1 = ((4 + q) ^ (lm & 7)) * 16;  // kk=1
  const char* ldsc = (const char*)lds;
  const char* p0A = ldsc + wm * 16384 + rowB;
  const char* p0B = ldsc + 32768 + (wn >> 1) * 16384 + (wn & 1) * 8192 + rowB;
  const char* p1A = p0A + 65536;
  const char* p1B = p0B + 65536;

  f32x4 acc[8][4] = {};
  bf16x8 aF[4][2], aG[4][2], bF[2][2], bG[2][2];

#define STG(p0, p1, kb, ldsOff)                                                  \
  {                                                                              \
    __builtin_amdgcn_global_load_lds((gvp)((p0) + (kb)),                         \
                                     (lvp)(lds + (ldsOff) + dst0), 16, 0, 0);    \
    __builtin_amdgcn_global_load_lds((gvp)((p1) + (kb)),                         \
                                     (lvp)(lds + (ldsOff) + dst1), 16, 0, 0);    \
  }
#define PH_SYNC()                                    \
  __builtin_amdgcn_s_barrier();                      \
  asm volatile("s_waitcnt lgkmcnt(0)" ::: "memory"); \
  __builtin_amdgcn_sched_barrier(0);
#define LDA(dst, p)                                                          \
  _Pragma("unroll") for (int i_ = 0; i_ < 4; ++i_) {                         \
    dst[i_][0] = *reinterpret_cast<const bf16x8*>((p) + i_ * 2048 + swz0);   \
    dst[i_][1] = *reinterpret_cast<const bf16x8*>((p) + i_ * 2048 + swz1);   \
  }
#define LDB(dst, p)                                                          \
  _Pragma("unroll") for (int j_ = 0; j_ < 2; ++j_) {                         \
    dst[j_][0] = *reinterpret_cast<const bf16x8*>((p) + j_ * 2048 + swz0);   \
    dst[j_][1] = *reinterpret_cast<const bf16x8*>((p) + j_ * 2048 + swz1);   \
  }

  // ---- prologue: Kt0 complete -> buf0; Kt1 A-halves -> buf1 ----
  STG(aS0, aS1, 0, 0);
  STG(aS2, aS3, 0, 16384);
  STG(bS0, bS1, 0, 32768);
  STG(bS2, bS3, 0, 49152);
  STG(aS0, aS1, 64, 65536);
  STG(aS2, aS3, 64, 65536 + 16384);
  __builtin_amdgcn_sched_barrier(0);
  asm volatile("s_waitcnt vmcnt(4)" ::: "memory");
  __builtin_amdgcn_s_barrier();
  __builtin_amdgcn_sched_barrier(0);

  for (int it = 0; it < 8; ++it) {
    const int kb1 = it * 128 + 64;   // Kt j+1
    const int kb2 = it * 128 + 128;  // Kt j+2
    const int kb3 = it * 128 + 192;  // Kt j+3
    const bool pf = (it < 7);

    // ---- phase 1: buf0 quad(fih0,fjh0); stage B0(j+1)->buf1 ----
    LDA(aF, p0A);
    LDB(bF, p0B);
    STG(bS0, bS1, kb1, 65536 + 32768);
    PH_SYNC();
    mfma16<0, 0>(acc, aF, bF);
    __builtin_amdgcn_s_barrier();

    // ---- phase 2: quad(fih1,fjh0); stage B1(j+1)->buf1 ----
    LDA(aG, p0A + 8192);
    STG(bS2, bS3, kb1, 65536 + 49152);
    PH_SYNC();
    mfma16<4, 0>(acc, aG, bF);
    __builtin_amdgcn_s_barrier();

    // ---- phase 3: quad(fih0,fjh1); stage A0(j+2)->buf0 ----
    LDB(bG, p0B + 4096);
    if (pf) STG(aS0, aS1, kb2, 0);
    PH_SYNC();
    mfma16<0, 2>(acc, aF, bG);
    __builtin_amdgcn_s_barrier();

    // ---- phase 4: quad(fih1,fjh1); stage A1(j+2)->buf0; drain ----
    if (pf) STG(aS2, aS3, kb2, 16384);
    PH_SYNC();
    mfma16<4, 2>(acc, aG, bG);
    __builtin_amdgcn_sched_barrier(0);
    if (pf)
      asm volatile("s_waitcnt vmcnt(4)" ::: "memory");
    else
      asm volatile("s_waitcnt vmcnt(0)" ::: "memory");
    __builtin_amdgcn_s_barrier();
    __builtin_amdgcn_sched_barrier(0);

    // ---- phase 5: buf1 quad(fih0,fjh0); stage B0(j+2)->buf0 ----
    LDA(aF, p1A);
    LDB(bF, p1B);
    if (pf) STG(bS0, bS1, kb2, 32768);
    PH_SYNC();
    mfma16<0, 0>(acc, aF, bF);
    __builtin_amdgcn_s_barrier();

    // ---- phase 6: quad(fih1,fjh0); stage B1(j+2)->buf0 ----
    LDA(aG, p1A + 8192);
    if (pf) STG(bS2, bS3, kb2, 49152);
    PH_SYNC();
    mfma16<4, 0>(acc, aG, bF);
    __builtin_amdgcn_s_barrier();

    // ---- phase 7: quad(fih0,fjh1); stage A0(j+3)->buf1 ----
    LDB(bG, p1B + 4096);
    if (pf) STG(aS0, aS1, kb3, 65536);
    PH_SYNC();
    mfma16<0, 2>(acc, aF, bG);
    __builtin_amdgcn_s_barrier();

    // ---- phase 8: quad(fih1,fjh1); stage A1(j+3)->buf1; drain ----
    if (pf) STG(aS2, aS3, kb3, 65536 + 16384);
    PH_SYNC();
    mfma16<4, 2>(acc, aG, bG);
    if (it < 7) {
      __builtin_amdgcn_sched_barrier(0);
      asm volatile("s_waitcnt vmcnt(4)" ::: "memory");
      __builtin_amdgcn_s_barrier();
      __builtin_amdgcn_sched_barrier(0);
    }
  }
#undef STG
#undef PH_SYNC
#undef LDA
#undef LDB

  // ---- epilogue: C/D layout col=lane&15, row=(lane>>4)*4+r ----
#pragma unroll
  for (int fi = 0; fi < 8; ++fi) {
#pragma unroll
    for (int fj = 0; fj < 4; ++fj) {
      int n = bn * 256 + wn * 64 + fj * 16 + lm;
      float bv = bias[n];
#pragma unroll
      for (int r = 0; r < 4; ++r) {
        size_t m = bm * 256 + wm * 128 + fi * 16 + ((lane >> 4) * 4) + r;
        Cg[m * 1024 + n] = f2bf(acc[fi][fj][r] + bv);
      }
    }
  }
}

// ---------------- 128x128 gload_lds GEMM (Q/O; verified) -------------------
template <typename TOUT>
__global__ __launch_bounds__(256) void gemm_lds(const ushort* __restrict__ Ag,
                                                const ushort* __restrict__ Wg,
                                                const float* __restrict__ bias,
                                                TOUT* __restrict__ Cg) {
  constexpr int K = 1024;
  __shared__ ushort lA[128 * 64];
  __shared__ ushort lB[128 * 64];
  const int tid = threadIdx.x;
  const int lane = tid & 63;
  const int wave = tid >> 6;
  const int wr = (wave >> 1) * 64;
  const int wc = (wave & 1) * 64;
  const int d = blockIdx.x;
  const int bn = (d >> 3) & 7;
  const size_t bm = (size_t)(d & 7) * (gridDim.x >> 6) + (d >> 6);

  const ushort* aB = Ag + bm * 128 * K;
  const ushort* bB = Wg + (size_t)bn * 128 * K;
  const int srow = wave * 32 + (lane >> 3);
  const int scol = ((lane & 7) ^ (lane >> 3)) * 8;
  char* lAc = (char*)lA;
  char* lBc = (char*)lB;

  f32x4 acc[4][4] = {};

  for (int kt = 0; kt < K; kt += 64) {
    __syncthreads();
#pragma unroll
    for (int c = 0; c < 4; ++c) {
      __builtin_amdgcn_global_load_lds(
          (gvp)(aB + (size_t)(srow + c * 8) * K + kt + scol),
          (lvp)(lAc + wave * 4096 + c * 1024), 16, 0, 0);
      __builtin_amdgcn_global_load_lds(
          (gvp)(bB + (size_t)(srow + c * 8) * K + kt + scol),
          (lvp)(lBc + wave * 4096 + c * 1024), 16, 0, 0);
    }
    __syncthreads();
#pragma unroll
    for (int kk = 0; kk < 2; ++kk) {
      bf16x8 af[4], bg[4];
#pragma unroll
      for (int fi = 0; fi < 4; ++fi) {
        int r = wr + fi * 16 + (lane & 15);
        int byte = (r * 128 + kk * 64 + ((lane >> 4) * 16)) ^ ((r & 7) << 4);
        af[fi] = *reinterpret_cast<const bf16x8*>(lAc + byte);
      }
#pragma unroll
      for (int fj = 0; fj < 4; ++fj) {
        int r = wc + fj * 16 + (lane & 15);
        int byte = (r * 128 + kk * 64 + ((lane >> 4) * 16)) ^ ((r & 7) << 4);
        bg[fj] = *reinterpret_cast<const bf16x8*>(lBc + byte);
      }
#pragma unroll
      for (int fi = 0; fi < 4; ++fi)
#pragma unroll
        for (int fj = 0; fj < 4; ++fj)
          acc[fi][fj] = __builtin_amdgcn_mfma_f32_16x16x32_bf16(af[fi], bg[fj],
                                                                acc[fi][fj], 0, 0, 0);
    }
  }
#pragma unroll
  for (int fi = 0; fi < 4; ++fi) {
#pragma unroll
    for (int fj = 0; fj < 4; ++fj) {
      int n = bn * 128 + wc + fj * 16 + (lane & 15);
      float bv = bias[n];
#pragma unroll
      for (int r = 0; r < 4; ++r) {
        size_t m = bm * 128 + wr + fi * 16 + ((lane >> 4) * 4) + r;
        float val = acc[fi][fj][r] + bv;
        if constexpr (sizeof(TOUT) == 2)
          reinterpret_cast<ushort*>(Cg)[m * 1024 + n] = f2bf(val);
        else
          reinterpret_cast<float*>(Cg)[m * 1024 + n] = val;
      }
    }
  }
}

// ------------- reg-staged GEMM (fp32 A): fallback path only ---------------
template <typename TIN, typename TOUT>
__global__ __launch_bounds__(256) void gemm_bias(const TIN* __restrict__ Ag,
                                                 const float* __restrict__ Wg,
                                                 const float* __restrict__ bias,
                                                 TOUT* __restrict__ Cg) {
  constexpr int K = 1024;
  __shared__ char lA[128 * 64 * 2];
  __shared__ char lB[128 * 64 * 2];
  const int tid = threadIdx.x;
  const int lane = tid & 63;
  const int wave = tid >> 6;
  const int wr = (wave >> 1) * 64;
  const int wc = (wave & 1) * 64;
  const int bn = blockIdx.x;
  const size_t bm = blockIdx.y;

  const TIN* aBase = Ag + bm * 128 * K;
  const float* bBase = Wg + (size_t)bn * 128 * K;

  f32x4 acc[4][4] = {};

  for (int kt = 0; kt < K; kt += 64) {
    __syncthreads();
    if constexpr (sizeof(TIN) == 4) {
#pragma unroll
      for (int i = 0; i < 8; ++i) {
        int f = tid + i * 256;
        int row = f >> 4, c4 = f & 15;
        const float4 v = *reinterpret_cast<const float4*>(
            reinterpret_cast<const float*>(aBase) + (size_t)row * K + kt + c4 * 4);
        ushort4 pk;
        pk.x = f2bf(v.x); pk.y = f2bf(v.y); pk.z = f2bf(v.z); pk.w = f2bf(v.w);
        int byte = (row * 128 + c4 * 8) ^ ((row & 7) << 4);
        *reinterpret_cast<ushort4*>(lA + byte) = pk;
      }
    } else {
#pragma unroll
      for (int i = 0; i < 4; ++i) {
        int f = tid + i * 256;
        int row = f >> 3, c8 = f & 7;
        int4 v = *reinterpret_cast<const int4*>(
            reinterpret_cast<const ushort*>(aBase) + (size_t)row * K + kt + c8 * 8);
        int byte = (row * 128 + c8 * 16) ^ ((row & 7) << 4);
        *reinterpret_cast<int4*>(lA + byte) = v;
      }
    }
#pragma unroll
    for (int i = 0; i < 8; ++i) {
      int f = tid + i * 256;
      int row = f >> 4, c4 = f & 15;
      const float4 v =
          *reinterpret_cast<const float4*>(bBase + (size_t)row * K + kt + c4 * 4);
      ushort4 pk;
      pk.x = f2bf(v.x); pk.y = f2bf(v.y); pk.z = f2bf(v.z); pk.w = f2bf(v.w);
      int byte = (row * 128 + c4 * 8) ^ ((row & 7) << 4);
      *reinterpret_cast<ushort4*>(lB + byte) = pk;
    }
    __syncthreads();
#pragma unroll
    for (int kk = 0; kk < 2; ++kk) {
      bf16x8 af[4], bg[4];
#pragma unroll
      for (int fi = 0; fi < 4; ++fi) {
        int r = wr + fi * 16 + (lane & 15);
        int byte = (r * 128 + kk * 64 + ((lane >> 4) * 16)) ^ ((r & 7) << 4);
        af[fi] = *reinterpret_cast<const bf16x8*>(lA + byte);
      }
#pragma unroll
      for (int fj = 0; fj < 4; ++fj) {
        int r = wc + fj * 16 + (lane & 15);
        int byte = (r * 128 + kk * 64 + ((lane >> 4) * 16)) ^ ((r & 7) << 4);
        bg[fj] = *reinterpret_cast<const bf16x8*>(lB + byte);
      }
#pragma unroll
      for (int fi = 0; fi < 4; ++fi)
#pragma unroll
        for (int fj = 0; fj < 4; ++fj)
          acc[fi][fj] =
              __builtin_amdgcn_mfma_f32_16x16x32_bf16(af[fi], bg[fj], acc[fi][fj], 0, 0, 0);
    }
  }
#pragma unroll
  for (int fi = 0; fi < 4; ++fi) {
#pragma unroll
    for (int fj = 0; fj < 4; ++fj) {
      int n = bn * 128 + wc + fj * 16 + (lane & 15);
      float bv = bias[n];
#pragma unroll
      for (int r = 0; r < 4; ++r) {
        size_t m = bm * 128 + wr + fi * 16 + ((lane >> 4) * 4) + r;
        float val = acc[fi][fj][r] + bv;
        if constexpr (sizeof(TOUT) == 2)
          reinterpret_cast<ushort*>(Cg)[m * 1024 + n] = f2bf(val);
        else
          reinterpret_cast<float*>(Cg)[m * 1024 + n] = val;
      }
    }
  }
}

// ---------------- attention: one block per (b,s'), head-axis softmax ------
__global__ __launch_bounds__(512) void attn_kernel(const ushort* __restrict__ Q,
                                                   const ushort* __restrict__ Kl,
                                                   const ushort* __restrict__ Vl,
                                                   ushort* __restrict__ Aout) {
  const int bs = blockIdx.x;
  const int b = bs >> 11, sp = bs & 2047;
  const int tid = threadIdx.x;
  const int wave = tid >> 6, lane = tid & 63;

  __shared__ ushort qrow[1024];
  __shared__ float sc[16][32];
  __shared__ float attnw[16][32];
  __shared__ float mx[32], rinv[32];

  reinterpret_cast<uint*>(qrow)[tid] =
      reinterpret_cast<const uint*>(Q + (size_t)bs * 1024)[tid];
  __syncthreads();

  const int wp = lane & 31, half = lane >> 5;
#pragma unroll
  for (int hh = 0; hh < 2; ++hh) {
    const int h = wave * 2 + hh;
    const int s_k = h * 128 + (sp >> 4);
    const int w_k = (sp & 15) * 2 + (wp >> 4);
    const ushort* kp =
        Kl + (((size_t)(b * 2048 + s_k) * 32) + w_k) * 1024 + (wp & 15) * 64 + half * 32;
    const ushort* qp = qrow + h * 64 + half * 32;
    float dot = 0.f;
#pragma unroll
    for (int j = 0; j < 32; j += 8) {
      int4 kv = *reinterpret_cast<const int4*>(kp + j);
      int4 qv = *reinterpret_cast<const int4*>(qp + j);
      const ushort* ka = reinterpret_cast<const ushort*>(&kv);
      const ushort* qa = reinterpret_cast<const ushort*>(&qv);
#pragma unroll
      for (int t = 0; t < 8; ++t) dot += bf2f(ka[t]) * bf2f(qa[t]);
    }
    dot += __shfl_xor(dot, 32);
    if (half == 0) sc[h][wp] = dot * 0.125f;
  }
  __syncthreads();
  if (tid < 32) {
    float m = sc[0][tid];
#pragma unroll
    for (int h = 1; h < 16; ++h) m = fmaxf(m, sc[h][tid]);
    float s = 0.f;
#pragma unroll
    for (int h = 0; h < 16; ++h) s += __expf(sc[h][tid] - m);
    mx[tid] = m;
    rinv[tid] = 1.f / s;
  }
  __syncthreads();
  if (lane < 32) {
#pragma unroll
    for (int hh = 0; hh < 2; ++hh) {
      const int h = wave * 2 + hh;
      attnw[h][lane] = __expf(sc[h][lane] - mx[lane]) * rinv[lane];
    }
  }
  __syncthreads();
#pragma unroll
  for (int hh = 0; hh < 2; ++hh) {
    const int h = wave * 2 + hh;
    const int s_k = h * 128 + (sp >> 4);
    const size_t vb = (((size_t)(b * 2048 + s_k) * 32) + (sp & 15) * 2) * 1024;
    float a = 0.f;
#pragma unroll
    for (int w2 = 0; w2 < 32; ++w2) {
      float wgt = attnw[h][w2];
      a += wgt * bf2f(Vl[vb + (size_t)(w2 >> 4) * 1024 + (w2 & 15) * 64 + lane]);
    }
    Aout[(((size_t)(b * 16 + h)) * 2048 + sp) * 64 + lane] = f2bf(a);
  }
}

extern "C" void kernel_launch(void* const* d_in, const int* in_sizes, int n_in,
                              void* d_out, int out_size, void* d_ws, size_t ws_size,
                              hipStream_t stream) {
  const float* q = (const float*)d_in[0];
  const float* k = (const float*)d_in[1];
  const float* v = (const float*)d_in[2];
  const float* Wq = (const float*)d_in[3];
  const float* bq = (const float*)d_in[4];
  const float* Wk = (const float*)d_in[5];
  const float* bk = (const float*)d_in[6];
  const float* Wv = (const float*)d_in[7];
  const float* bv = (const float*)d_in[8];
  const float* Wo = (const float*)d_in[9];
  const float* bo = (const float*)d_in[10];
  float* out = (float*)d_out;

  char* ws = (char*)d_ws;
  const size_t MB = 1u << 20;
  ushort* Qlin = (ushort*)ws;                    // 8 MiB
  ushort* Aws  = (ushort*)(ws + 8 * MB);         // 8 MiB
  ushort* wkbf = (ushort*)(ws + 16 * MB);        // 2 MiB
  ushort* wvbf = (ushort*)(ws + 18 * MB);        // 2 MiB
  ushort* wqbf = (ushort*)(ws + 20 * MB);        // 2 MiB
  ushort* wobf = (ushort*)(ws + 22 * MB);        // 2 MiB
  ushort* qbf  = (ushort*)(ws + 24 * MB);        // 8 MiB
  ushort* Klin = (ushort*)(ws + 32 * MB);        // 256 MiB
  ushort* Vlin = (ushort*)(ws + 288 * MB);       // 256 MiB
  ushort* kvbf = (ushort*)(ws + 544 * MB);       // 256 MiB (k then v)
  const bool full = ws_size >= 800 * MB;

  const long NKV = 134217728L;  // 2*2048*32*1024

  if (full) {
    cast_kernel<<<dim3(512), 256, 0, stream>>>(Wq, wqbf, 1048576L);
    cast_kernel<<<dim3(512), 256, 0, stream>>>(Wk, wkbf, 1048576L);
    cast_kernel<<<dim3(512), 256, 0, stream>>>(Wv, wvbf, 1048576L);
    cast_kernel<<<dim3(512), 256, 0, stream>>>(Wo, wobf, 1048576L);
    cast_kernel<<<dim3(2048), 256, 0, stream>>>(q, qbf, 4194304L);
    gemm_lds<ushort><<<dim3(256), 256, 0, stream>>>(qbf, wqbf, bq, Qlin);
    cast_kernel<<<dim3(4096), 256, 0, stream>>>(k, kvbf, NKV);
    gemm_big<<<dim3(2048), 512, 0, stream>>>(kvbf, wkbf, bk, Klin);
    cast_kernel<<<dim3(4096), 256, 0, stream>>>(v, kvbf, NKV);
    gemm_big<<<dim3(2048), 512, 0, stream>>>(kvbf, wvbf, bv, Vlin);
    attn_kernel<<<dim3(4096), dim3(512), 0, stream>>>(Qlin, Klin, Vlin, Aws);
    gemm_lds<float><<<dim3(256), 256, 0, stream>>>(Aws, wobf, bo, out);
  } else {
    gemm_bias<float, ushort><<<dim3(8, 32), 256, 0, stream>>>(q, Wq, bq, Qlin);
    gemm_bias<float, ushort><<<dim3(8, 1024), 256, 0, stream>>>(k, Wk, bk, Klin);
    gemm_bias<float, ushort><<<dim3(8, 1024), 256, 0, stream>>>(v, Wv, bv, Vlin);
    attn_kernel<<<dim3(4096), dim3(512), 0, stream>>>(Qlin, Klin, Vlin, Aws);
    gemm_bias<ushort, float><<<dim3(8, 32), 256, 0, stream>>>(Aws, Wo, bo, out);
  }
}